// Round 2
// baseline (706.728 us; speedup 1.0000x reference)
//
#include <hip/hip_runtime.h>

// GCN 2-layer: transform-first + CSR-by-dst gather aggregation.
// Round-2 change: degree histograms now use per-XCD partial arrays with
// XCD-LOCAL (workgroup-scope) atomics -- device-scope atomicAdd was
// write-through to the memory-side coherence point (200MB WRITE_SIZE,
// 245us). Each block reads HW_REG_XCC_ID and increments only its own
// XCD's partial; partial[x] is touched exclusively by XCD x, so TCC-local
// RMW is race-free, and kernel-end release flushes L2 for the reduce pass.
//   memset cursor+partials -> k_deg_part -> k_deg_reduce (degrees+norms) ->
//   prefix-scan deg_in -> bucket edges by dst (device-scope cursor atomics,
//   still; next target) -> GEMM1 -> AGG1 -> GEMM2 -> AGG2
// Math identity: segsum(h[src]) @ W == segsum((h@W)[src]); per-row scales
// commute with the right-multiply. Layer-2 gather shrinks 64 -> 32 features.

#define NN 100000
#define NE 3200000
#define HID 64
#define NOUTF 30
#define NXCD 8

#define TPB 256
#define SCAN_CHUNK 1024
#define NSCAN ((NN + SCAN_CHUNK - 1) / SCAN_CHUNK)  // 98

// ---------------- degrees: per-XCD partial histograms ----------------
// p layout: p[x*NN + n] = partial out-degree on XCD x; p[(NXCD+x)*NN + n] =
// partial in-degree on XCD x.
__global__ __launch_bounds__(TPB) void k_deg_part(const int* __restrict__ src,
                                                  const int* __restrict__ dst,
                                                  int* __restrict__ p) {
  unsigned xcd;
  asm("s_getreg_b32 %0, hwreg(HW_REG_XCC_ID)" : "=s"(xcd));
  int* po = p + (size_t)xcd * NN;
  int* pi = p + (size_t)(NXCD + xcd) * NN;
  int e = blockIdx.x * TPB + threadIdx.x;
  if (e < NE) {
    __hip_atomic_fetch_add(&po[src[e]], 1, __ATOMIC_RELAXED, __HIP_MEMORY_SCOPE_WORKGROUP);
    __hip_atomic_fetch_add(&pi[dst[e]], 1, __ATOMIC_RELAXED, __HIP_MEMORY_SCOPE_WORKGROUP);
  }
}

__global__ __launch_bounds__(TPB) void k_deg_reduce(const int* __restrict__ p,
                                                    int* __restrict__ deg_out,
                                                    int* __restrict__ deg_in,
                                                    float* __restrict__ norm_out,
                                                    float* __restrict__ norm_in) {
  int n = blockIdx.x * TPB + threadIdx.x;
  if (n < NN) {
    int so = 0, si = 0;
#pragma unroll
    for (int x = 0; x < NXCD; ++x) {
      so += p[(size_t)x * NN + n];
      si += p[(size_t)(NXCD + x) * NN + n];
    }
    deg_out[n] = so;
    deg_in[n] = si;
    norm_out[n] = (so > 0) ? rsqrtf((float)so) : 0.0f;
    norm_in[n] = (si > 0) ? rsqrtf((float)si) : 0.0f;
  }
}

// ---------------- prefix scan of deg_in -> row_ptr (3 kernels) ----------------
__global__ __launch_bounds__(TPB) void k_scan1(const int* __restrict__ deg,
                                               int* __restrict__ bsums) {
  int t = threadIdx.x;
  int base = blockIdx.x * SCAN_CHUNK;
  int s = 0;
  for (int i = t; i < SCAN_CHUNK; i += TPB) {
    int idx = base + i;
    if (idx < NN) s += deg[idx];
  }
  __shared__ int red[TPB];
  red[t] = s;
  __syncthreads();
  for (int off = TPB / 2; off > 0; off >>= 1) {
    if (t < off) red[t] += red[t + off];
    __syncthreads();
  }
  if (t == 0) bsums[blockIdx.x] = red[0];
}

__global__ __launch_bounds__(128) void k_scan2(int* __restrict__ bsums) {
  int t = threadIdx.x;
  __shared__ int lds[128];
  int v = (t < NSCAN) ? bsums[t] : 0;
  int acc = v;
  lds[t] = acc;
  __syncthreads();
  for (int off = 1; off < 128; off <<= 1) {
    int add = (t >= off) ? lds[t - off] : 0;
    __syncthreads();
    acc += add;
    lds[t] = acc;
    __syncthreads();
  }
  if (t < NSCAN) bsums[t] = acc - v;  // exclusive block offsets
}

__global__ __launch_bounds__(TPB) void k_scan3(const int* __restrict__ deg,
                                               const int* __restrict__ bsums,
                                               int* __restrict__ row_ptr) {
  int t = threadIdx.x;
  int base = blockIdx.x * SCAN_CHUNK + t * 4;
  int v[4];
  int s = 0;
#pragma unroll
  for (int j = 0; j < 4; ++j) {
    int idx = base + j;
    v[j] = (idx < NN) ? deg[idx] : 0;
    s += v[j];
  }
  __shared__ int lds[TPB];
  int acc = s;
  lds[t] = acc;
  __syncthreads();
  for (int off = 1; off < TPB; off <<= 1) {
    int add = (t >= off) ? lds[t - off] : 0;
    __syncthreads();
    acc += add;
    lds[t] = acc;
    __syncthreads();
  }
  int run = bsums[blockIdx.x] + (acc - s);
#pragma unroll
  for (int j = 0; j < 4; ++j) {
    int idx = base + j;
    if (idx < NN) row_ptr[idx] = run;
    run += v[j];
  }
  if (blockIdx.x == 0 && t == 0) row_ptr[NN] = NE;  // total in-degree == NE
}

// ---------------- bucket edges by dst (counting sort) ----------------
__global__ __launch_bounds__(TPB) void k_bucket(const int* __restrict__ src,
                                                const int* __restrict__ dst,
                                                const int* __restrict__ row_ptr,
                                                int* __restrict__ cursor,
                                                int* __restrict__ src_sorted) {
  int e = blockIdx.x * TPB + threadIdx.x;
  if (e < NE) {
    int d = dst[e];
    int p = row_ptr[d] + atomicAdd(&cursor[d], 1);
    src_sorted[p] = src[e];
  }
}

// ---------------- GEMM1: xt[n] = norm_out[n] * (x[n] @ W1)  [64 -> 64] -------
__global__ __launch_bounds__(TPB) void k_gemm1(const float4* __restrict__ x4,
                                               const float* __restrict__ W1,
                                               const float* __restrict__ norm_out,
                                               float* __restrict__ xt) {
  int lane = threadIdx.x & 63;
  int wid = (blockIdx.x * TPB + threadIdx.x) >> 6;
  int nwaves = gridDim.x * (TPB / 64);
  float w[64];
#pragma unroll
  for (int k = 0; k < 64; ++k) w[k] = W1[k * 64 + lane];  // coalesced row reads
  int m = lane >> 4, q = lane & 15;
  for (int grp = wid; grp < NN / 4; grp += nwaves) {
    int nbase = grp * 4;
    float4 rv = x4[(nbase + m) * 16 + q];  // 1KB fully-coalesced: 4 rows
    int r0 = __float_as_int(rv.x), r1 = __float_as_int(rv.y);
    int r2 = __float_as_int(rv.z), r3 = __float_as_int(rv.w);
    float acc[4] = {0.f, 0.f, 0.f, 0.f};
#pragma unroll
    for (int mm = 0; mm < 4; ++mm) {
#pragma unroll
      for (int ql = 0; ql < 16; ++ql) {
        int sl = mm * 16 + ql;
        acc[mm] = fmaf(__int_as_float(__builtin_amdgcn_readlane(r0, sl)), w[ql * 4 + 0], acc[mm]);
        acc[mm] = fmaf(__int_as_float(__builtin_amdgcn_readlane(r1, sl)), w[ql * 4 + 1], acc[mm]);
        acc[mm] = fmaf(__int_as_float(__builtin_amdgcn_readlane(r2, sl)), w[ql * 4 + 2], acc[mm]);
        acc[mm] = fmaf(__int_as_float(__builtin_amdgcn_readlane(r3, sl)), w[ql * 4 + 3], acc[mm]);
      }
    }
#pragma unroll
    for (int mm = 0; mm < 4; ++mm) {
      int n = nbase + mm;
      xt[n * 64 + lane] = norm_out[n] * acc[mm];  // coalesced 256B store
    }
  }
}

// ---------------- GEMM2: h1t[n][0:32] = norm_out[n]*(h1[n] @ W2), cols 30,31=0
__global__ __launch_bounds__(TPB) void k_gemm2(const float4* __restrict__ h1_4,
                                               const float* __restrict__ W2,
                                               const float* __restrict__ norm_out,
                                               float* __restrict__ h1t) {
  int lane = threadIdx.x & 63;
  int wid = (blockIdx.x * TPB + threadIdx.x) >> 6;
  int nwaves = gridDim.x * (TPB / 64);
  int gclamp = (lane < NOUTF) ? lane : 0;  // keep loads in-bounds
  float w[64];
#pragma unroll
  for (int k = 0; k < 64; ++k) {
    float wv = W2[k * NOUTF + gclamp];
    w[k] = (lane < NOUTF) ? wv : 0.f;
  }
  int m = lane >> 4, q = lane & 15;
  for (int grp = wid; grp < NN / 4; grp += nwaves) {
    int nbase = grp * 4;
    float4 rv = h1_4[(nbase + m) * 16 + q];
    int r0 = __float_as_int(rv.x), r1 = __float_as_int(rv.y);
    int r2 = __float_as_int(rv.z), r3 = __float_as_int(rv.w);
    float acc[4] = {0.f, 0.f, 0.f, 0.f};
#pragma unroll
    for (int mm = 0; mm < 4; ++mm) {
#pragma unroll
      for (int ql = 0; ql < 16; ++ql) {
        int sl = mm * 16 + ql;
        acc[mm] = fmaf(__int_as_float(__builtin_amdgcn_readlane(r0, sl)), w[ql * 4 + 0], acc[mm]);
        acc[mm] = fmaf(__int_as_float(__builtin_amdgcn_readlane(r1, sl)), w[ql * 4 + 1], acc[mm]);
        acc[mm] = fmaf(__int_as_float(__builtin_amdgcn_readlane(r2, sl)), w[ql * 4 + 2], acc[mm]);
        acc[mm] = fmaf(__int_as_float(__builtin_amdgcn_readlane(r3, sl)), w[ql * 4 + 3], acc[mm]);
      }
    }
    if (lane < 32) {
#pragma unroll
      for (int mm = 0; mm < 4; ++mm) {
        int n = nbase + mm;
        float v = (lane < NOUTF) ? norm_out[n] * acc[mm] : 0.f;
        h1t[n * 32 + lane] = v;  // pad cols 30,31 with zeros
      }
    }
  }
}

// ---------------- AGG1: h1[n] = relu(norm_in[n]*segsum(xt[src]) + b1) -------
__global__ __launch_bounds__(TPB) void k_agg1(const float4* __restrict__ xt4,
                                              const int* __restrict__ src_sorted,
                                              const int* __restrict__ row_ptr,
                                              const float* __restrict__ norm_in,
                                              const float* __restrict__ b1,
                                              float4* __restrict__ h1_4) {
  int node = (blockIdx.x * TPB + threadIdx.x) >> 6;
  int lane = threadIdx.x & 63;
  int slot = lane >> 4;  // 0..3
  int fl = lane & 15;    // float4 index: features fl*4..fl*4+3
  int beg = row_ptr[node];
  int end = row_ptr[node + 1];
  float4 a0 = make_float4(0.f, 0.f, 0.f, 0.f);
  float4 a1 = make_float4(0.f, 0.f, 0.f, 0.f);
  int e = beg + slot;
  for (; e + 4 < end; e += 8) {
    int s0 = src_sorted[e];
    int s1 = src_sorted[e + 4];
    float4 v0 = xt4[s0 * 16 + fl];
    float4 v1 = xt4[s1 * 16 + fl];
    a0.x += v0.x; a0.y += v0.y; a0.z += v0.z; a0.w += v0.w;
    a1.x += v1.x; a1.y += v1.y; a1.z += v1.z; a1.w += v1.w;
  }
  if (e < end) {
    int s0 = src_sorted[e];
    float4 v0 = xt4[s0 * 16 + fl];
    a0.x += v0.x; a0.y += v0.y; a0.z += v0.z; a0.w += v0.w;
  }
  a0.x += a1.x; a0.y += a1.y; a0.z += a1.z; a0.w += a1.w;
#pragma unroll
  for (int off = 16; off <= 32; off <<= 1) {
    a0.x += __shfl_xor(a0.x, off);
    a0.y += __shfl_xor(a0.y, off);
    a0.z += __shfl_xor(a0.z, off);
    a0.w += __shfl_xor(a0.w, off);
  }
  if (slot == 0) {
    float ni = norm_in[node];
    float4 b = reinterpret_cast<const float4*>(b1)[fl];
    float4 r;
    r.x = fmaxf(fmaf(a0.x, ni, b.x), 0.f);
    r.y = fmaxf(fmaf(a0.y, ni, b.y), 0.f);
    r.z = fmaxf(fmaf(a0.z, ni, b.z), 0.f);
    r.w = fmaxf(fmaf(a0.w, ni, b.w), 0.f);
    h1_4[node * 16 + fl] = r;
  }
}

// ---------------- AGG2: out[n] = norm_in[n]*segsum(h1t[src]) + b2 -----------
__global__ __launch_bounds__(TPB) void k_agg2(const float4* __restrict__ h1t4,
                                              const int* __restrict__ src_sorted,
                                              const int* __restrict__ row_ptr,
                                              const float* __restrict__ norm_in,
                                              const float* __restrict__ b2,
                                              float* __restrict__ out) {
  int node = (blockIdx.x * TPB + threadIdx.x) >> 6;
  int lane = threadIdx.x & 63;
  int slot = lane >> 3;  // 0..7
  int fl = lane & 7;     // float4 index within 32 padded features
  int beg = row_ptr[node];
  int end = row_ptr[node + 1];
  float4 a0 = make_float4(0.f, 0.f, 0.f, 0.f);
  float4 a1 = make_float4(0.f, 0.f, 0.f, 0.f);
  int e = beg + slot;
  for (; e + 8 < end; e += 16) {
    int s0 = src_sorted[e];
    int s1 = src_sorted[e + 8];
    float4 v0 = h1t4[s0 * 8 + fl];
    float4 v1 = h1t4[s1 * 8 + fl];
    a0.x += v0.x; a0.y += v0.y; a0.z += v0.z; a0.w += v0.w;
    a1.x += v1.x; a1.y += v1.y; a1.z += v1.z; a1.w += v1.w;
  }
  if (e < end) {
    int s0 = src_sorted[e];
    float4 v0 = h1t4[s0 * 8 + fl];
    a0.x += v0.x; a0.y += v0.y; a0.z += v0.z; a0.w += v0.w;
  }
  a0.x += a1.x; a0.y += a1.y; a0.z += a1.z; a0.w += a1.w;
#pragma unroll
  for (int off = 8; off <= 32; off <<= 1) {
    a0.x += __shfl_xor(a0.x, off);
    a0.y += __shfl_xor(a0.y, off);
    a0.z += __shfl_xor(a0.z, off);
    a0.w += __shfl_xor(a0.w, off);
  }
  if (slot == 0) {
    float ni = norm_in[node];
    int f0 = fl * 4;
    float vals[4] = {a0.x, a0.y, a0.z, a0.w};
#pragma unroll
    for (int c = 0; c < 4; ++c) {
      int f = f0 + c;
      if (f < NOUTF) out[node * NOUTF + f] = fmaf(vals[c], ni, b2[f]);
    }
  }
}

extern "C" void kernel_launch(void* const* d_in, const int* in_sizes, int n_in,
                              void* d_out, int out_size, void* d_ws, size_t ws_size,
                              hipStream_t stream) {
  (void)in_sizes; (void)n_in; (void)out_size; (void)ws_size;
  const float* x = (const float*)d_in[0];
  const int* src = (const int*)d_in[1];
  const int* dst = (const int*)d_in[2];
  const float* W1 = (const float*)d_in[3];
  const float* b1 = (const float*)d_in[4];
  const float* W2 = (const float*)d_in[5];
  const float* b2 = (const float*)d_in[6];
  float* out = (float*)d_out;

  // Workspace layout (bytes), total 66,400,640 — all 16B-aligned.
  char* ws = (char*)d_ws;
  int* deg_out = (int*)(ws + 0);              //   400,000 (written by reduce)
  int* deg_in = (int*)(ws + 400000);          //   400,000 (written by reduce)
  int* cursor = (int*)(ws + 800000);          //   400,000 (memset)
  int* row_ptr = (int*)(ws + 1200000);        //   400,128 (100001 ints, padded)
  int* bsums = (int*)(ws + 1600128);          //       512
  float* norm_out = (float*)(ws + 1600640);   //   400,000
  float* norm_in = (float*)(ws + 2000640);    //   400,000
  int* src_sorted = (int*)(ws + 2400640);     // 12,800,000
  float* xt = (float*)(ws + 15200640);        // 25,600,000 (reused as h1t later)
  float* h1 = (float*)(ws + 40800640);        // 25,600,000
  float* h1t = xt;  // xt dead after k_agg1; h1t needs only 12.8 MB
  // Per-XCD degree partials (16*NN ints = 6.4MB) alias the xt region: they
  // are fully consumed by k_deg_reduce before k_gemm1 writes xt.
  int* p_deg = (int*)(ws + 15200640);

  hipMemsetAsync(cursor, 0, 400000, stream);
  hipMemsetAsync(p_deg, 0, (size_t)2 * NXCD * NN * 4, stream);
  k_deg_part<<<NE / TPB, TPB, 0, stream>>>(src, dst, p_deg);
  k_deg_reduce<<<(NN + TPB - 1) / TPB, TPB, 0, stream>>>(p_deg, deg_out, deg_in, norm_out, norm_in);
  k_scan1<<<NSCAN, TPB, 0, stream>>>(deg_in, bsums);
  k_scan2<<<1, 128, 0, stream>>>(bsums);
  k_scan3<<<NSCAN, TPB, 0, stream>>>(deg_in, bsums, row_ptr);
  k_bucket<<<NE / TPB, TPB, 0, stream>>>(src, dst, row_ptr, cursor, src_sorted);
  k_gemm1<<<1024, TPB, 0, stream>>>((const float4*)x, W1, norm_out, xt);
  k_agg1<<<NN / 4, TPB, 0, stream>>>((const float4*)xt, src_sorted, row_ptr, norm_in, b1, (float4*)h1);
  k_gemm2<<<1024, TPB, 0, stream>>>((const float4*)h1, W2, norm_out, h1t);
  k_agg2<<<NN / 4, TPB, 0, stream>>>((const float4*)h1t, src_sorted, row_ptr, norm_in, b2, out);
}

// Round 3
// 382.170 us; speedup vs baseline: 1.8493x; 1.8493x over previous
//
#include <hip/hip_runtime.h>

// GCN 2-layer, round 3: ZERO global atomics.
// Round-2 lesson: global-memory atomics on gfx950 are write-through to the
// memory-side coherence point regardless of scope argument (240us, 200MB
// WRITE_SIZE for 6.4M int atomics). So the CSR build is now an atomic-free
// two-level bucket sort:
//   A: per-block LDS histogram of dst>>7  -> H[bin][block]
//   B: exclusive scan of H (bin-major)    -> disjoint output slice per (bin,blk)
//   C: scatter packed=(src<<7)|(dst&127) via LDS cursors (no global atomics)
//   D: per-bucket 128-bin LDS counting sort -> src_sorted + row_ptr + norm_in
//   E: out-degree via LDS-tiled histogram (7 ranges x 16K bins x 64 slices)
// Then transform-first GEMMs + CSR gather aggregation as before:
//   GEMM1 xt = norm_out*(x@W1) -> AGG1 h1 = relu(norm_in*gather-sum + b1) ->
//   GEMM2 h1t = norm_out*(h1@W2) [30->32 pad] -> AGG2 out.
// Identity: segsum(h[src]) @ W == segsum((h@W)[src]).

#define NN 100000
#define NE 3200000
#define NOUTF 30
#define TPB 256

// coarse bucketing
#define CSHIFT 7
#define CB 128                           // nodes per coarse bucket
#define NB ((NN + CB - 1) / CB)          // 782
#define CHUNK 8192
#define NBLK ((NE + CHUNK - 1) / CHUNK)  // 391
#define HL (NB * NBLK)                   // 305,762
#define POOL 14336                       // fine-sort staging (57,344 B LDS)

// generic scan over HL
#define GCH 1024
#define NSC ((HL + GCH - 1) / GCH)       // 299 (must be <= 512)

// out-degree tiled histogram
#define RBINS 16384                      // 64KB LDS
#define NRANGE ((NN + RBINS - 1) / RBINS)  // 7
#define NSLICE 64
#define SLICE_E (NE / NSLICE)            // 50,000

// ---------------- A: coarse histogram (LDS atomics only) ----------------
__global__ __launch_bounds__(TPB) void k_coarse_hist(const int* __restrict__ dst,
                                                     int* __restrict__ H) {
  __shared__ int hist[NB];
  int t = threadIdx.x, k = blockIdx.x;
  for (int b = t; b < NB; b += TPB) hist[b] = 0;
  __syncthreads();
  int beg = k * CHUNK, end = min(NE, beg + CHUNK);
  for (int i = beg + t; i < end; i += TPB)
    atomicAdd(&hist[dst[i] >> CSHIFT], 1);
  __syncthreads();
  for (int b = t; b < NB; b += TPB) H[b * NBLK + k] = hist[b];
}

// ---------------- B: generic 3-kernel exclusive scan over H[HL] ----------
__global__ __launch_bounds__(TPB) void g_scan1(const int* __restrict__ a,
                                               int* __restrict__ bsums) {
  int t = threadIdx.x;
  int base = blockIdx.x * GCH + t * 4;
  int s = 0;
#pragma unroll
  for (int j = 0; j < 4; ++j) { int idx = base + j; if (idx < HL) s += a[idx]; }
  __shared__ int red[TPB];
  red[t] = s; __syncthreads();
  for (int off = TPB / 2; off > 0; off >>= 1) {
    if (t < off) red[t] += red[t + off];
    __syncthreads();
  }
  if (t == 0) bsums[blockIdx.x] = red[0];
}

__global__ __launch_bounds__(512) void g_scan2(int* __restrict__ bsums) {
  int t = threadIdx.x;
  __shared__ int lds[512];
  int v = (t < NSC) ? bsums[t] : 0;
  int acc = v; lds[t] = acc; __syncthreads();
  for (int off = 1; off < 512; off <<= 1) {
    int add = (t >= off) ? lds[t - off] : 0; __syncthreads();
    acc += add; lds[t] = acc; __syncthreads();
  }
  if (t < NSC) bsums[t] = acc - v;  // exclusive
}

__global__ __launch_bounds__(TPB) void g_scan3(int* __restrict__ a,
                                               const int* __restrict__ bsums) {
  int t = threadIdx.x;
  int base = blockIdx.x * GCH + t * 4;
  int v[4]; int s = 0;
#pragma unroll
  for (int j = 0; j < 4; ++j) {
    int idx = base + j;
    v[j] = (idx < HL) ? a[idx] : 0;
    s += v[j];
  }
  __shared__ int lds[TPB];
  int acc = s; lds[t] = acc; __syncthreads();
  for (int off = 1; off < TPB; off <<= 1) {
    int add = (t >= off) ? lds[t - off] : 0; __syncthreads();
    acc += add; lds[t] = acc; __syncthreads();
  }
  int run = bsums[blockIdx.x] + (acc - s);
#pragma unroll
  for (int j = 0; j < 4; ++j) {
    int idx = base + j;
    if (idx < HL) a[idx] = run;  // in-place exclusive
    run += v[j];
  }
}

// ---------------- C: coarse scatter via LDS cursors ----------------------
__global__ __launch_bounds__(TPB) void k_scatter_coarse(const int* __restrict__ src,
                                                        const int* __restrict__ dst,
                                                        const int* __restrict__ Hs,
                                                        int* __restrict__ packed) {
  __shared__ int cur[NB];
  int t = threadIdx.x, k = blockIdx.x;
  for (int b = t; b < NB; b += TPB) cur[b] = Hs[b * NBLK + k];
  __syncthreads();
  int beg = k * CHUNK, end = min(NE, beg + CHUNK);
  for (int i = beg + t; i < end; i += TPB) {
    int s = src[i], d = dst[i];
    int p = atomicAdd(&cur[d >> CSHIFT], 1);          // LDS atomic
    packed[p] = (s << CSHIFT) | (d & (CB - 1));       // 24-bit payload
  }
}

// ---------------- D: per-bucket fine counting sort -----------------------
__global__ __launch_bounds__(TPB) void k_fine_sort(const int* __restrict__ Hs,
                                                   const int* __restrict__ packed,
                                                   int* __restrict__ src_sorted,
                                                   int* __restrict__ row_ptr,
                                                   float* __restrict__ norm_in) {
  __shared__ int hist[CB], scn[CB], cur[CB];
  __shared__ int pool[POOL];
  int t = threadIdx.x, b = blockIdx.x;
  int seg_beg = Hs[b * NBLK];
  int seg_end = (b + 1 < NB) ? Hs[(b + 1) * NBLK] : NE;
  int cnt = seg_end - seg_beg;
  if (t < CB) hist[t] = 0;
  __syncthreads();
  for (int i = seg_beg + t; i < seg_end; i += TPB)
    atomicAdd(&hist[packed[i] & (CB - 1)], 1);
  __syncthreads();
  if (t < CB) scn[t] = hist[t];
  __syncthreads();
  for (int off = 1; off < CB; off <<= 1) {   // Hillis-Steele inclusive
    int add = (t >= off && t < CB) ? scn[t - off] : 0;
    __syncthreads();
    if (t < CB) scn[t] += add;
    __syncthreads();
  }
  if (t < CB) {
    int excl = scn[t] - hist[t];
    cur[t] = excl;
    int node = b * CB + t;
    if (node < NN) {
      row_ptr[node] = seg_beg + excl;
      norm_in[node] = (hist[t] > 0) ? rsqrtf((float)hist[t]) : 0.0f;
    }
  }
  if (b == NB - 1 && t == 0) row_ptr[NN] = NE;
  __syncthreads();
  for (int i = seg_beg + t; i < seg_end; i += TPB) {
    int v = packed[i];
    int p = atomicAdd(&cur[v & (CB - 1)], 1);         // LDS atomic
    int sv = v >> CSHIFT;
    if (p < POOL) pool[p] = sv;
    else src_sorted[seg_beg + p] = sv;                 // overflow fallback
  }
  __syncthreads();
  int lim = min(cnt, POOL);
  for (int i = t; i < lim; i += TPB) src_sorted[seg_beg + i] = pool[i];  // coalesced
}

// ---------------- E: out-degree tiled histogram (no global atomics) ------
__global__ __launch_bounds__(TPB) void k_outdeg_hist(const int* __restrict__ src,
                                                     int* __restrict__ P) {
  __shared__ int hist[RBINS];  // 64KB
  int t = threadIdx.x;
  int r = blockIdx.x >> 6;   // range 0..NRANGE-1
  int s = blockIdx.x & 63;   // slice 0..63
  int rbase = r * RBINS;
  for (int i = t; i < RBINS; i += TPB) hist[i] = 0;
  __syncthreads();
  int beg = s * SLICE_E, end = beg + SLICE_E;
  for (int i = beg + t; i < end; i += TPB) {
    int v = src[i] - rbase;
    if ((unsigned)v < RBINS) atomicAdd(&hist[v], 1);
  }
  __syncthreads();
  int nb = min(RBINS, NN - rbase);
  for (int i = t; i < nb; i += TPB) P[s * NN + rbase + i] = hist[i];
}

__global__ __launch_bounds__(TPB) void k_outdeg_reduce(const int* __restrict__ P,
                                                       float* __restrict__ norm_out) {
  int n = blockIdx.x * TPB + threadIdx.x;
  if (n < NN) {
    int s = 0;
#pragma unroll
    for (int k = 0; k < NSLICE; ++k) s += P[k * NN + n];
    norm_out[n] = (s > 0) ? rsqrtf((float)s) : 0.0f;
  }
}

// ---------------- GEMM1: xt[n] = norm_out[n] * (x[n] @ W1)  [64 -> 64] ----
__global__ __launch_bounds__(TPB) void k_gemm1(const float4* __restrict__ x4,
                                               const float* __restrict__ W1,
                                               const float* __restrict__ norm_out,
                                               float* __restrict__ xt) {
  int lane = threadIdx.x & 63;
  int wid = (blockIdx.x * TPB + threadIdx.x) >> 6;
  int nwaves = gridDim.x * (TPB / 64);
  float w[64];
#pragma unroll
  for (int k = 0; k < 64; ++k) w[k] = W1[k * 64 + lane];
  int m = lane >> 4, q = lane & 15;
  for (int grp = wid; grp < NN / 4; grp += nwaves) {
    int nbase = grp * 4;
    float4 rv = x4[(nbase + m) * 16 + q];
    int r0 = __float_as_int(rv.x), r1 = __float_as_int(rv.y);
    int r2 = __float_as_int(rv.z), r3 = __float_as_int(rv.w);
    float acc[4] = {0.f, 0.f, 0.f, 0.f};
#pragma unroll
    for (int mm = 0; mm < 4; ++mm) {
#pragma unroll
      for (int ql = 0; ql < 16; ++ql) {
        int sl = mm * 16 + ql;
        acc[mm] = fmaf(__int_as_float(__builtin_amdgcn_readlane(r0, sl)), w[ql * 4 + 0], acc[mm]);
        acc[mm] = fmaf(__int_as_float(__builtin_amdgcn_readlane(r1, sl)), w[ql * 4 + 1], acc[mm]);
        acc[mm] = fmaf(__int_as_float(__builtin_amdgcn_readlane(r2, sl)), w[ql * 4 + 2], acc[mm]);
        acc[mm] = fmaf(__int_as_float(__builtin_amdgcn_readlane(r3, sl)), w[ql * 4 + 3], acc[mm]);
      }
    }
#pragma unroll
    for (int mm = 0; mm < 4; ++mm) {
      int n = nbase + mm;
      xt[n * 64 + lane] = norm_out[n] * acc[mm];
    }
  }
}

// -------- GEMM2: h1t[n][0:32] = norm_out[n]*(h1[n] @ W2), cols 30,31 = 0 --
__global__ __launch_bounds__(TPB) void k_gemm2(const float4* __restrict__ h1_4,
                                               const float* __restrict__ W2,
                                               const float* __restrict__ norm_out,
                                               float* __restrict__ h1t) {
  int lane = threadIdx.x & 63;
  int wid = (blockIdx.x * TPB + threadIdx.x) >> 6;
  int nwaves = gridDim.x * (TPB / 64);
  int gclamp = (lane < NOUTF) ? lane : 0;
  float w[64];
#pragma unroll
  for (int k = 0; k < 64; ++k) {
    float wv = W2[k * NOUTF + gclamp];
    w[k] = (lane < NOUTF) ? wv : 0.f;
  }
  int m = lane >> 4, q = lane & 15;
  for (int grp = wid; grp < NN / 4; grp += nwaves) {
    int nbase = grp * 4;
    float4 rv = h1_4[(nbase + m) * 16 + q];
    int r0 = __float_as_int(rv.x), r1 = __float_as_int(rv.y);
    int r2 = __float_as_int(rv.z), r3 = __float_as_int(rv.w);
    float acc[4] = {0.f, 0.f, 0.f, 0.f};
#pragma unroll
    for (int mm = 0; mm < 4; ++mm) {
#pragma unroll
      for (int ql = 0; ql < 16; ++ql) {
        int sl = mm * 16 + ql;
        acc[mm] = fmaf(__int_as_float(__builtin_amdgcn_readlane(r0, sl)), w[ql * 4 + 0], acc[mm]);
        acc[mm] = fmaf(__int_as_float(__builtin_amdgcn_readlane(r1, sl)), w[ql * 4 + 1], acc[mm]);
        acc[mm] = fmaf(__int_as_float(__builtin_amdgcn_readlane(r2, sl)), w[ql * 4 + 2], acc[mm]);
        acc[mm] = fmaf(__int_as_float(__builtin_amdgcn_readlane(r3, sl)), w[ql * 4 + 3], acc[mm]);
      }
    }
    if (lane < 32) {
#pragma unroll
      for (int mm = 0; mm < 4; ++mm) {
        int n = nbase + mm;
        float v = (lane < NOUTF) ? norm_out[n] * acc[mm] : 0.f;
        h1t[n * 32 + lane] = v;
      }
    }
  }
}

// -------- AGG1: h1[n] = relu(norm_in[n]*segsum(xt[src]) + b1) -------------
__global__ __launch_bounds__(TPB) void k_agg1(const float4* __restrict__ xt4,
                                              const int* __restrict__ src_sorted,
                                              const int* __restrict__ row_ptr,
                                              const float* __restrict__ norm_in,
                                              const float* __restrict__ b1,
                                              float4* __restrict__ h1_4) {
  int node = (blockIdx.x * TPB + threadIdx.x) >> 6;
  int lane = threadIdx.x & 63;
  int slot = lane >> 4;
  int fl = lane & 15;
  int beg = row_ptr[node];
  int end = row_ptr[node + 1];
  float4 a0 = make_float4(0.f, 0.f, 0.f, 0.f);
  float4 a1 = make_float4(0.f, 0.f, 0.f, 0.f);
  int e = beg + slot;
  for (; e + 4 < end; e += 8) {
    int s0 = src_sorted[e];
    int s1 = src_sorted[e + 4];
    float4 v0 = xt4[s0 * 16 + fl];
    float4 v1 = xt4[s1 * 16 + fl];
    a0.x += v0.x; a0.y += v0.y; a0.z += v0.z; a0.w += v0.w;
    a1.x += v1.x; a1.y += v1.y; a1.z += v1.z; a1.w += v1.w;
  }
  if (e < end) {
    int s0 = src_sorted[e];
    float4 v0 = xt4[s0 * 16 + fl];
    a0.x += v0.x; a0.y += v0.y; a0.z += v0.z; a0.w += v0.w;
  }
  a0.x += a1.x; a0.y += a1.y; a0.z += a1.z; a0.w += a1.w;
#pragma unroll
  for (int off = 16; off <= 32; off <<= 1) {
    a0.x += __shfl_xor(a0.x, off);
    a0.y += __shfl_xor(a0.y, off);
    a0.z += __shfl_xor(a0.z, off);
    a0.w += __shfl_xor(a0.w, off);
  }
  if (slot == 0) {
    float ni = norm_in[node];
    float4 b = reinterpret_cast<const float4*>(b1)[fl];
    float4 r;
    r.x = fmaxf(fmaf(a0.x, ni, b.x), 0.f);
    r.y = fmaxf(fmaf(a0.y, ni, b.y), 0.f);
    r.z = fmaxf(fmaf(a0.z, ni, b.z), 0.f);
    r.w = fmaxf(fmaf(a0.w, ni, b.w), 0.f);
    h1_4[node * 16 + fl] = r;
  }
}

// -------- AGG2: out[n] = norm_in[n]*segsum(h1t[src]) + b2 -----------------
__global__ __launch_bounds__(TPB) void k_agg2(const float4* __restrict__ h1t4,
                                              const int* __restrict__ src_sorted,
                                              const int* __restrict__ row_ptr,
                                              const float* __restrict__ norm_in,
                                              const float* __restrict__ b2,
                                              float* __restrict__ out) {
  int node = (blockIdx.x * TPB + threadIdx.x) >> 6;
  int lane = threadIdx.x & 63;
  int slot = lane >> 3;
  int fl = lane & 7;
  int beg = row_ptr[node];
  int end = row_ptr[node + 1];
  float4 a0 = make_float4(0.f, 0.f, 0.f, 0.f);
  float4 a1 = make_float4(0.f, 0.f, 0.f, 0.f);
  int e = beg + slot;
  for (; e + 8 < end; e += 16) {
    int s0 = src_sorted[e];
    int s1 = src_sorted[e + 8];
    float4 v0 = h1t4[s0 * 8 + fl];
    float4 v1 = h1t4[s1 * 8 + fl];
    a0.x += v0.x; a0.y += v0.y; a0.z += v0.z; a0.w += v0.w;
    a1.x += v1.x; a1.y += v1.y; a1.z += v1.z; a1.w += v1.w;
  }
  if (e < end) {
    int s0 = src_sorted[e];
    float4 v0 = h1t4[s0 * 8 + fl];
    a0.x += v0.x; a0.y += v0.y; a0.z += v0.z; a0.w += v0.w;
  }
  a0.x += a1.x; a0.y += a1.y; a0.z += a1.z; a0.w += a1.w;
#pragma unroll
  for (int off = 8; off <= 32; off <<= 1) {
    a0.x += __shfl_xor(a0.x, off);
    a0.y += __shfl_xor(a0.y, off);
    a0.z += __shfl_xor(a0.z, off);
    a0.w += __shfl_xor(a0.w, off);
  }
  if (slot == 0) {
    float ni = norm_in[node];
    int f0 = fl * 4;
    float vals[4] = {a0.x, a0.y, a0.z, a0.w};
#pragma unroll
    for (int c = 0; c < 4; ++c) {
      int f = f0 + c;
      if (f < NOUTF) out[node * NOUTF + f] = fmaf(vals[c], ni, b2[f]);
    }
  }
}

extern "C" void kernel_launch(void* const* d_in, const int* in_sizes, int n_in,
                              void* d_out, int out_size, void* d_ws, size_t ws_size,
                              hipStream_t stream) {
  (void)in_sizes; (void)n_in; (void)out_size; (void)ws_size;
  const float* x = (const float*)d_in[0];
  const int* src = (const int*)d_in[1];
  const int* dst = (const int*)d_in[2];
  const float* W1 = (const float*)d_in[3];
  const float* b1 = (const float*)d_in[4];
  const float* W2 = (const float*)d_in[5];
  const float* b2 = (const float*)d_in[6];
  float* out = (float*)d_out;

  // Workspace layout (bytes), total 66,425,344; all offsets 16B-aligned.
  // Region2 (25.6MB) time-shares: packed (C->D), P (E), h1 (agg1->gemm2).
  // Region1 (25.6MB) time-shares: xt (gemm1->agg1), h1t (gemm2->agg2).
  char* ws = (char*)d_ws;
  int* row_ptr = (int*)(ws + 0);               //   400,128 (100001 ints pad)
  float* norm_out = (float*)(ws + 400128);     //   400,000
  float* norm_in = (float*)(ws + 800128);      //   400,000
  int* H = (int*)(ws + 1200128);               // 1,223,168 (305,762 ints pad)
  int* bsums = (int*)(ws + 2423296);           //     2,048 (512 ints)
  int* src_sorted = (int*)(ws + 2425344);      // 12,800,000
  int* packed = (int*)(ws + 15225344);         // Region2 head: 12,800,000
  int* P = (int*)(ws + 15225344);              // Region2: 25,600,000 (after D)
  float* h1 = (float*)(ws + 15225344);         // Region2 (after reduce)
  float* xt = (float*)(ws + 40825344);         // Region1: 25,600,000
  float* h1t = xt;                              // Region1 reuse (12.8MB)

  k_coarse_hist<<<NBLK, TPB, 0, stream>>>(dst, H);
  g_scan1<<<NSC, TPB, 0, stream>>>(H, bsums);
  g_scan2<<<1, 512, 0, stream>>>(bsums);
  g_scan3<<<NSC, TPB, 0, stream>>>(H, bsums);
  k_scatter_coarse<<<NBLK, TPB, 0, stream>>>(src, dst, H, packed);
  k_fine_sort<<<NB, TPB, 0, stream>>>(H, packed, src_sorted, row_ptr, norm_in);
  k_outdeg_hist<<<NRANGE * NSLICE, TPB, 0, stream>>>(src, P);
  k_outdeg_reduce<<<(NN + TPB - 1) / TPB, TPB, 0, stream>>>(P, norm_out);
  k_gemm1<<<1024, TPB, 0, stream>>>((const float4*)x, W1, norm_out, xt);
  k_agg1<<<NN / 4, TPB, 0, stream>>>((const float4*)xt, src_sorted, row_ptr, norm_in, b1, (float4*)h1);
  k_gemm2<<<1024, TPB, 0, stream>>>((const float4*)h1, W2, norm_out, h1t);
  k_agg2<<<NN / 4, TPB, 0, stream>>>((const float4*)h1t, src_sorted, row_ptr, norm_in, b2, out);
}

// Round 4
// 325.381 us; speedup vs baseline: 2.1720x; 1.1745x over previous
//
#include <hip/hip_runtime.h>

// GCN 2-layer, round 4: bf16 gather payloads (RNE), f32 accumulation.
// Round-3 profile: k_agg1 = 103us, FETCH 352MB (logical 819MB, 57% cache-
// absorbed), 3.5TB/s, VALUBusy 22% -> gather-BYTES-bound. Fix: store the
// transformed features (xt, h1t) as bf16: rows 256B->128B / 128B->64B,
// footprints 25.6->12.8MB / 12.8->6.4MB. Decode = shl/and + f32 add.
// CSR build stays the round-3 atomic-free two-level bucket sort:
//   A coarse LDS hist of dst>>7 -> B scan -> C scatter packed via LDS
//   cursors -> D per-bucket 128-bin LDS counting sort (-> row_ptr, norm_in)
//   E out-degree tiled LDS histogram -> norm_out.
// Identity: segsum(h[src]) @ W == segsum((h@W)[src]) (transform-first).

#define NN 100000
#define NE 3200000
#define NOUTF 30
#define TPB 256

// coarse bucketing
#define CSHIFT 7
#define CB 128                           // nodes per coarse bucket
#define NB ((NN + CB - 1) / CB)          // 782
#define CHUNK 8192
#define NBLK ((NE + CHUNK - 1) / CHUNK)  // 391
#define HL (NB * NBLK)                   // 305,762
#define POOL 14336                       // fine-sort staging (57,344 B LDS)

// generic scan over HL
#define GCH 1024
#define NSC ((HL + GCH - 1) / GCH)       // 299 (<= 512)

// out-degree tiled histogram
#define RBINS 16384
#define NRANGE ((NN + RBINS - 1) / RBINS)  // 7
#define NSLICE 64
#define SLICE_E (NE / NSLICE)            // 50,000

__device__ __forceinline__ unsigned short f2bf(float f) {  // round-nearest-even
  unsigned u = __float_as_uint(f);
  u = (u + 0x7FFFu + ((u >> 16) & 1u)) >> 16;
  return (unsigned short)u;
}

// accumulate 8 bf16 (one uint4) into 8 f32
__device__ __forceinline__ void acc8(float* a, const uint4& u) {
  a[0] += __uint_as_float(u.x << 16);
  a[1] += __uint_as_float(u.x & 0xFFFF0000u);
  a[2] += __uint_as_float(u.y << 16);
  a[3] += __uint_as_float(u.y & 0xFFFF0000u);
  a[4] += __uint_as_float(u.z << 16);
  a[5] += __uint_as_float(u.z & 0xFFFF0000u);
  a[6] += __uint_as_float(u.w << 16);
  a[7] += __uint_as_float(u.w & 0xFFFF0000u);
}

// ---------------- A: coarse histogram (LDS atomics only) ----------------
__global__ __launch_bounds__(TPB) void k_coarse_hist(const int* __restrict__ dst,
                                                     int* __restrict__ H) {
  __shared__ int hist[NB];
  int t = threadIdx.x, k = blockIdx.x;
  for (int b = t; b < NB; b += TPB) hist[b] = 0;
  __syncthreads();
  int beg = k * CHUNK, end = min(NE, beg + CHUNK);
  for (int i = beg + t; i < end; i += TPB)
    atomicAdd(&hist[dst[i] >> CSHIFT], 1);
  __syncthreads();
  for (int b = t; b < NB; b += TPB) H[b * NBLK + k] = hist[b];
}

// ---------------- B: generic 3-kernel exclusive scan over H[HL] ----------
__global__ __launch_bounds__(TPB) void g_scan1(const int* __restrict__ a,
                                               int* __restrict__ bsums) {
  int t = threadIdx.x;
  int base = blockIdx.x * GCH + t * 4;
  int s = 0;
#pragma unroll
  for (int j = 0; j < 4; ++j) { int idx = base + j; if (idx < HL) s += a[idx]; }
  __shared__ int red[TPB];
  red[t] = s; __syncthreads();
  for (int off = TPB / 2; off > 0; off >>= 1) {
    if (t < off) red[t] += red[t + off];
    __syncthreads();
  }
  if (t == 0) bsums[blockIdx.x] = red[0];
}

__global__ __launch_bounds__(512) void g_scan2(int* __restrict__ bsums) {
  int t = threadIdx.x;
  __shared__ int lds[512];
  int v = (t < NSC) ? bsums[t] : 0;
  int acc = v; lds[t] = acc; __syncthreads();
  for (int off = 1; off < 512; off <<= 1) {
    int add = (t >= off) ? lds[t - off] : 0; __syncthreads();
    acc += add; lds[t] = acc; __syncthreads();
  }
  if (t < NSC) bsums[t] = acc - v;  // exclusive
}

__global__ __launch_bounds__(TPB) void g_scan3(int* __restrict__ a,
                                               const int* __restrict__ bsums) {
  int t = threadIdx.x;
  int base = blockIdx.x * GCH + t * 4;
  int v[4]; int s = 0;
#pragma unroll
  for (int j = 0; j < 4; ++j) {
    int idx = base + j;
    v[j] = (idx < HL) ? a[idx] : 0;
    s += v[j];
  }
  __shared__ int lds[TPB];
  int acc = s; lds[t] = acc; __syncthreads();
  for (int off = 1; off < TPB; off <<= 1) {
    int add = (t >= off) ? lds[t - off] : 0; __syncthreads();
    acc += add; lds[t] = acc; __syncthreads();
  }
  int run = bsums[blockIdx.x] + (acc - s);
#pragma unroll
  for (int j = 0; j < 4; ++j) {
    int idx = base + j;
    if (idx < HL) a[idx] = run;  // in-place exclusive
    run += v[j];
  }
}

// ---------------- C: coarse scatter via LDS cursors ----------------------
__global__ __launch_bounds__(TPB) void k_scatter_coarse(const int* __restrict__ src,
                                                        const int* __restrict__ dst,
                                                        const int* __restrict__ Hs,
                                                        int* __restrict__ packed) {
  __shared__ int cur[NB];
  int t = threadIdx.x, k = blockIdx.x;
  for (int b = t; b < NB; b += TPB) cur[b] = Hs[b * NBLK + k];
  __syncthreads();
  int beg = k * CHUNK, end = min(NE, beg + CHUNK);
  for (int i = beg + t; i < end; i += TPB) {
    int s = src[i], d = dst[i];
    int p = atomicAdd(&cur[d >> CSHIFT], 1);          // LDS atomic
    packed[p] = (s << CSHIFT) | (d & (CB - 1));       // 24-bit payload
  }
}

// ---------------- D: per-bucket fine counting sort -----------------------
__global__ __launch_bounds__(TPB) void k_fine_sort(const int* __restrict__ Hs,
                                                   const int* __restrict__ packed,
                                                   int* __restrict__ src_sorted,
                                                   int* __restrict__ row_ptr,
                                                   float* __restrict__ norm_in) {
  __shared__ int hist[CB], scn[CB], cur[CB];
  __shared__ int pool[POOL];
  int t = threadIdx.x, b = blockIdx.x;
  int seg_beg = Hs[b * NBLK];
  int seg_end = (b + 1 < NB) ? Hs[(b + 1) * NBLK] : NE;
  int cnt = seg_end - seg_beg;
  if (t < CB) hist[t] = 0;
  __syncthreads();
  for (int i = seg_beg + t; i < seg_end; i += TPB)
    atomicAdd(&hist[packed[i] & (CB - 1)], 1);
  __syncthreads();
  if (t < CB) scn[t] = hist[t];
  __syncthreads();
  for (int off = 1; off < CB; off <<= 1) {   // Hillis-Steele inclusive
    int add = (t >= off && t < CB) ? scn[t - off] : 0;
    __syncthreads();
    if (t < CB) scn[t] += add;
    __syncthreads();
  }
  if (t < CB) {
    int excl = scn[t] - hist[t];
    cur[t] = excl;
    int node = b * CB + t;
    if (node < NN) {
      row_ptr[node] = seg_beg + excl;
      norm_in[node] = (hist[t] > 0) ? rsqrtf((float)hist[t]) : 0.0f;
    }
  }
  if (b == NB - 1 && t == 0) row_ptr[NN] = NE;
  __syncthreads();
  for (int i = seg_beg + t; i < seg_end; i += TPB) {
    int v = packed[i];
    int p = atomicAdd(&cur[v & (CB - 1)], 1);         // LDS atomic
    int sv = v >> CSHIFT;
    if (p < POOL) pool[p] = sv;
    else src_sorted[seg_beg + p] = sv;                 // overflow fallback
  }
  __syncthreads();
  int lim = min(cnt, POOL);
  for (int i = t; i < lim; i += TPB) src_sorted[seg_beg + i] = pool[i];  // coalesced
}

// ---------------- E: out-degree tiled histogram (no global atomics) ------
__global__ __launch_bounds__(TPB) void k_outdeg_hist(const int* __restrict__ src,
                                                     int* __restrict__ P) {
  __shared__ int hist[RBINS];  // 64KB
  int t = threadIdx.x;
  int r = blockIdx.x >> 6;   // range
  int s = blockIdx.x & 63;   // slice
  int rbase = r * RBINS;
  for (int i = t; i < RBINS; i += TPB) hist[i] = 0;
  __syncthreads();
  int beg = s * SLICE_E, end = beg + SLICE_E;
  for (int i = beg + t; i < end; i += TPB) {
    int v = src[i] - rbase;
    if ((unsigned)v < RBINS) atomicAdd(&hist[v], 1);
  }
  __syncthreads();
  int nb = min(RBINS, NN - rbase);
  for (int i = t; i < nb; i += TPB) P[s * NN + rbase + i] = hist[i];
}

__global__ __launch_bounds__(TPB) void k_outdeg_reduce(const int* __restrict__ P,
                                                       float* __restrict__ norm_out) {
  int n = blockIdx.x * TPB + threadIdx.x;
  if (n < NN) {
    int s = 0;
#pragma unroll
    for (int k = 0; k < NSLICE; ++k) s += P[k * NN + n];
    norm_out[n] = (s > 0) ? rsqrtf((float)s) : 0.0f;
  }
}

// ------ GEMM1: xt_b[n] = bf16( norm_out[n] * (x[n] @ W1) )  [64 -> 64] ----
__global__ __launch_bounds__(TPB) void k_gemm1(const float4* __restrict__ x4,
                                               const float* __restrict__ W1,
                                               const float* __restrict__ norm_out,
                                               unsigned short* __restrict__ xt_b) {
  int lane = threadIdx.x & 63;
  int wid = (blockIdx.x * TPB + threadIdx.x) >> 6;
  int nwaves = gridDim.x * (TPB / 64);
  float w[64];
#pragma unroll
  for (int k = 0; k < 64; ++k) w[k] = W1[k * 64 + lane];
  int m = lane >> 4, q = lane & 15;
  for (int grp = wid; grp < NN / 4; grp += nwaves) {
    int nbase = grp * 4;
    float4 rv = x4[(nbase + m) * 16 + q];
    int r0 = __float_as_int(rv.x), r1 = __float_as_int(rv.y);
    int r2 = __float_as_int(rv.z), r3 = __float_as_int(rv.w);
    float acc[4] = {0.f, 0.f, 0.f, 0.f};
#pragma unroll
    for (int mm = 0; mm < 4; ++mm) {
#pragma unroll
      for (int ql = 0; ql < 16; ++ql) {
        int sl = mm * 16 + ql;
        acc[mm] = fmaf(__int_as_float(__builtin_amdgcn_readlane(r0, sl)), w[ql * 4 + 0], acc[mm]);
        acc[mm] = fmaf(__int_as_float(__builtin_amdgcn_readlane(r1, sl)), w[ql * 4 + 1], acc[mm]);
        acc[mm] = fmaf(__int_as_float(__builtin_amdgcn_readlane(r2, sl)), w[ql * 4 + 2], acc[mm]);
        acc[mm] = fmaf(__int_as_float(__builtin_amdgcn_readlane(r3, sl)), w[ql * 4 + 3], acc[mm]);
      }
    }
#pragma unroll
    for (int mm = 0; mm < 4; ++mm) {
      int n = nbase + mm;
      xt_b[n * 64 + lane] = f2bf(norm_out[n] * acc[mm]);  // 128B/row coalesced
    }
  }
}

// -- GEMM2: h1t_b[n][0:32] = bf16( norm_out[n]*(h1[n] @ W2) ), cols 30,31=0 -
__global__ __launch_bounds__(TPB) void k_gemm2(const float4* __restrict__ h1_4,
                                               const float* __restrict__ W2,
                                               const float* __restrict__ norm_out,
                                               unsigned short* __restrict__ h1t_b) {
  int lane = threadIdx.x & 63;
  int wid = (blockIdx.x * TPB + threadIdx.x) >> 6;
  int nwaves = gridDim.x * (TPB / 64);
  int gclamp = (lane < NOUTF) ? lane : 0;
  float w[64];
#pragma unroll
  for (int k = 0; k < 64; ++k) {
    float wv = W2[k * NOUTF + gclamp];
    w[k] = (lane < NOUTF) ? wv : 0.f;
  }
  int m = lane >> 4, q = lane & 15;
  for (int grp = wid; grp < NN / 4; grp += nwaves) {
    int nbase = grp * 4;
    float4 rv = h1_4[(nbase + m) * 16 + q];
    int r0 = __float_as_int(rv.x), r1 = __float_as_int(rv.y);
    int r2 = __float_as_int(rv.z), r3 = __float_as_int(rv.w);
    float acc[4] = {0.f, 0.f, 0.f, 0.f};
#pragma unroll
    for (int mm = 0; mm < 4; ++mm) {
#pragma unroll
      for (int ql = 0; ql < 16; ++ql) {
        int sl = mm * 16 + ql;
        acc[mm] = fmaf(__int_as_float(__builtin_amdgcn_readlane(r0, sl)), w[ql * 4 + 0], acc[mm]);
        acc[mm] = fmaf(__int_as_float(__builtin_amdgcn_readlane(r1, sl)), w[ql * 4 + 1], acc[mm]);
        acc[mm] = fmaf(__int_as_float(__builtin_amdgcn_readlane(r2, sl)), w[ql * 4 + 2], acc[mm]);
        acc[mm] = fmaf(__int_as_float(__builtin_amdgcn_readlane(r3, sl)), w[ql * 4 + 3], acc[mm]);
      }
    }
    if (lane < 32) {
#pragma unroll
      for (int mm = 0; mm < 4; ++mm) {
        int n = nbase + mm;
        unsigned short v = (lane < NOUTF) ? f2bf(norm_out[n] * acc[mm]) : (unsigned short)0;
        h1t_b[n * 32 + lane] = v;  // 64B/row
      }
    }
  }
}

// -- AGG1: h1[n] = relu(norm_in[n]*segsum(xt_b[src]) + b1); bf16 in, f32 out
// 8 edge-slots x 8 lanes x uint4(8 bf16) = 128B row per 8 lanes.
__global__ __launch_bounds__(TPB) void k_agg1(const uint4* __restrict__ xt4,
                                              const int* __restrict__ src_sorted,
                                              const int* __restrict__ row_ptr,
                                              const float* __restrict__ norm_in,
                                              const float* __restrict__ b1,
                                              float4* __restrict__ h1_4) {
  int node = (blockIdx.x * TPB + threadIdx.x) >> 6;
  int lane = threadIdx.x & 63;
  int slot = lane >> 3;  // 0..7
  int fl = lane & 7;     // uint4 index within 128B row
  int beg = row_ptr[node];
  int end = row_ptr[node + 1];
  float a[8] = {0.f, 0.f, 0.f, 0.f, 0.f, 0.f, 0.f, 0.f};
  int e = beg + slot;
  for (; e + 8 < end; e += 16) {
    int s0 = src_sorted[e];
    int s1 = src_sorted[e + 8];
    uint4 u0 = xt4[s0 * 8 + fl];
    uint4 u1 = xt4[s1 * 8 + fl];
    acc8(a, u0);
    acc8(a, u1);
  }
  if (e < end) {
    uint4 u0 = xt4[src_sorted[e] * 8 + fl];
    acc8(a, u0);
  }
#pragma unroll
  for (int off = 8; off <= 32; off <<= 1) {
#pragma unroll
    for (int j = 0; j < 8; ++j) a[j] += __shfl_xor(a[j], off);
  }
  if (slot == 0) {
    float ni = norm_in[node];
    float4 blo = reinterpret_cast<const float4*>(b1)[fl * 2];
    float4 bhi = reinterpret_cast<const float4*>(b1)[fl * 2 + 1];
    float4 r0, r1;
    r0.x = fmaxf(fmaf(a[0], ni, blo.x), 0.f);
    r0.y = fmaxf(fmaf(a[1], ni, blo.y), 0.f);
    r0.z = fmaxf(fmaf(a[2], ni, blo.z), 0.f);
    r0.w = fmaxf(fmaf(a[3], ni, blo.w), 0.f);
    r1.x = fmaxf(fmaf(a[4], ni, bhi.x), 0.f);
    r1.y = fmaxf(fmaf(a[5], ni, bhi.y), 0.f);
    r1.z = fmaxf(fmaf(a[6], ni, bhi.z), 0.f);
    r1.w = fmaxf(fmaf(a[7], ni, bhi.w), 0.f);
    h1_4[node * 16 + fl * 2] = r0;
    h1_4[node * 16 + fl * 2 + 1] = r1;
  }
}

// -- AGG2: out[n] = norm_in[n]*segsum(h1t_b[src]) + b2; bf16 in, f32 out ---
// 16 edge-slots x 4 lanes x uint4 = 64B row per 4 lanes.
__global__ __launch_bounds__(TPB) void k_agg2(const uint4* __restrict__ h1t4,
                                              const int* __restrict__ src_sorted,
                                              const int* __restrict__ row_ptr,
                                              const float* __restrict__ norm_in,
                                              const float* __restrict__ b2,
                                              float* __restrict__ out) {
  int node = (blockIdx.x * TPB + threadIdx.x) >> 6;
  int lane = threadIdx.x & 63;
  int slot = lane >> 2;  // 0..15
  int fl = lane & 3;     // uint4 index within 64B row
  int beg = row_ptr[node];
  int end = row_ptr[node + 1];
  float a[8] = {0.f, 0.f, 0.f, 0.f, 0.f, 0.f, 0.f, 0.f};
  int e = beg + slot;
  for (; e + 16 < end; e += 32) {
    int s0 = src_sorted[e];
    int s1 = src_sorted[e + 16];
    uint4 u0 = h1t4[s0 * 4 + fl];
    uint4 u1 = h1t4[s1 * 4 + fl];
    acc8(a, u0);
    acc8(a, u1);
  }
  if (e < end) {
    uint4 u0 = h1t4[src_sorted[e] * 4 + fl];
    acc8(a, u0);
  }
#pragma unroll
  for (int off = 4; off <= 32; off <<= 1) {
#pragma unroll
    for (int j = 0; j < 8; ++j) a[j] += __shfl_xor(a[j], off);
  }
  if (slot == 0) {
    float ni = norm_in[node];
    int f0 = fl * 8;  // features f0..f0+7 (f0+6,f0+7 invalid when fl==3... only 30,31)
    float2* ob = (float2*)(out + (size_t)node * NOUTF);  // rows 120B, 8B-aligned
#pragma unroll
    for (int p = 0; p < 4; ++p) {
      int f = f0 + p * 2;
      if (f < NOUTF) {  // f==30 (fl==3,p==3) dropped; pairs stay in-bounds
        float2 v;
        v.x = fmaf(a[p * 2], ni, b2[f]);
        v.y = fmaf(a[p * 2 + 1], ni, b2[f + 1]);
        ob[f >> 1] = v;
      }
    }
  }
}

extern "C" void kernel_launch(void* const* d_in, const int* in_sizes, int n_in,
                              void* d_out, int out_size, void* d_ws, size_t ws_size,
                              hipStream_t stream) {
  (void)in_sizes; (void)n_in; (void)out_size; (void)ws_size;
  const float* x = (const float*)d_in[0];
  const int* src = (const int*)d_in[1];
  const int* dst = (const int*)d_in[2];
  const float* W1 = (const float*)d_in[3];
  const float* b1 = (const float*)d_in[4];
  const float* W2 = (const float*)d_in[5];
  const float* b2 = (const float*)d_in[6];
  float* out = (float*)d_out;

  // Workspace layout (bytes); all offsets 16B-aligned.
  // Region2 (25.6MB) time-shares: packed (C->D), P (E), h1 f32 (agg1->gemm2).
  // Region1 (12.8MB) time-shares: xt_b bf16 (gemm1->agg1), h1t_b bf16 (gemm2->agg2).
  char* ws = (char*)d_ws;
  int* row_ptr = (int*)(ws + 0);               //   400,128 (100001 ints pad)
  float* norm_out = (float*)(ws + 400128);     //   400,000
  float* norm_in = (float*)(ws + 800128);      //   400,000
  int* H = (int*)(ws + 1200128);               // 1,223,168 (305,762 ints pad)
  int* bsums = (int*)(ws + 2423296);           //     2,048 (512 ints)
  int* src_sorted = (int*)(ws + 2425344);      // 12,800,000
  int* packed = (int*)(ws + 15225344);         // Region2 head: 12,800,000
  int* P = (int*)(ws + 15225344);              // Region2: 25,600,000
  float* h1 = (float*)(ws + 15225344);         // Region2
  unsigned short* xt_b = (unsigned short*)(ws + 40825344);   // Region1: 12,800,000
  unsigned short* h1t_b = xt_b;                 // Region1 reuse (6.4MB)

  k_coarse_hist<<<NBLK, TPB, 0, stream>>>(dst, H);
  g_scan1<<<NSC, TPB, 0, stream>>>(H, bsums);
  g_scan2<<<1, 512, 0, stream>>>(bsums);
  g_scan3<<<NSC, TPB, 0, stream>>>(H, bsums);
  k_scatter_coarse<<<NBLK, TPB, 0, stream>>>(src, dst, H, packed);
  k_fine_sort<<<NB, TPB, 0, stream>>>(H, packed, src_sorted, row_ptr, norm_in);
  k_outdeg_hist<<<NRANGE * NSLICE, TPB, 0, stream>>>(src, P);
  k_outdeg_reduce<<<(NN + TPB - 1) / TPB, TPB, 0, stream>>>(P, norm_out);
  k_gemm1<<<1024, TPB, 0, stream>>>((const float4*)x, W1, norm_out, xt_b);
  k_agg1<<<NN / 4, TPB, 0, stream>>>((const uint4*)xt_b, src_sorted, row_ptr, norm_in, b1, (float4*)h1);
  k_gemm2<<<1024, TPB, 0, stream>>>((const float4*)h1, W2, norm_out, h1t_b);
  k_agg2<<<NN / 4, TPB, 0, stream>>>((const uint4*)h1t_b, src_sorted, row_ptr, norm_in, b2, out);
}